// Round 8
// baseline (139.879 us; speedup 1.0000x reference)
//
#include <hip/hip_runtime.h>

// N=524288, D=9, E=2, H=128, M=32, O=2, K=1.
// LAYOUT (confirmed R6): d_in fp32, d_out FP32 (N*2 outputs + 1 loss).
// NUMERICS: pure fp32; per-token fmaf chains identical to accepted kernel.
//
// R8: K=8 tokens/thread + per-lane LDS weight reads. Validated models:
//  - DS b128 ~12cyc/instr even same-address broadcast (R5: predicted 3x
//    VALU-bound -> 38.5us measured). Weight delivery = 36 cyc DS/j/wave,
//    FIXED; so flip the ratio: K=8 -> DS 144 < VALU 192 cyc/j per CU.
//  - v_readlane ~26cyc effective (R7 fit) -> banned.
//  - SMEM s_load unpipelined (R0-R4) -> banned.
// No uniformity branch: lanes use their own expert base (<=2 distinct
// addrs/wave, same banks (6144B = 0 mod 32 banks) -> 2-way = free, m136).
// Straddling thread's <=7 wrong-expert tokens fixed by a small second
// pass on lanes 0..6 of wave 0. Grid 256 = 1 block/CU, LDS 90KB.
#define NTOK 524288
#define TPB  256
#define TOKB 2048             // tokens per block (8 per thread)
#define NBLK (NTOK / TOKB)    // 256

__device__ __forceinline__ float bf2f(unsigned short u) {
    union { unsigned int i; float f; } v;
    v.i = ((unsigned int)u) << 16;
    return v.f;
}

// input load: raw fp32 (bf16-buffer fallback kept purely as safety)
__device__ __forceinline__ float ldq(const void* p, int i, bool f32) {
    if (f32) return ((const float*)p)[i];
    return bf2f(((const unsigned short*)p)[i]);
}

// ---------------------------------------------------------------------------
// Prep: detect buffer dtype (parallel probe), zero counter, stage w_gate,
// fold W2@Wout (+ b2@Wout + bout), pack per-hidden-unit weights.
// wpack layout (expert-major): wpack[e*1536 + j*12 + {0..8:W1col, 9:b1,
// 10..11:W2'}] — 48B records, 16B-aligned.
// ---------------------------------------------------------------------------
__global__ void prep_kernel(const void* __restrict__ num_prop,
                            const void* __restrict__ wgate,
                            const void* __restrict__ W1,
                            const void* __restrict__ b1,
                            const void* __restrict__ W2,
                            const void* __restrict__ b2,
                            const void* __restrict__ Wout,
                            const void* __restrict__ bout,
                            unsigned int* __restrict__ cnt1,
                            int* __restrict__ flag,
                            float* __restrict__ bpp,
                            float* __restrict__ wgf,
                            float* __restrict__ wpack)
{
    __shared__ unsigned int bad;
    __shared__ int sflag;
    const int t = threadIdx.x;
    if (t == 0) { bad = 0u; *cnt1 = 0u; }
    __syncthreads();
    if (t < 72) {   // parallel dtype probe
        const unsigned short* u = (const unsigned short*)num_prop;
        int e = (u[t] >> 7) & 0xFF;
        if (e < 64 || e > 191) atomicOr(&bad, 1u);
    }
    __syncthreads();
    if (t == 0) { sflag = (int)bad; *flag = (int)bad; }
    __syncthreads();
    const bool f32 = (sflag != 0);

    if (t < 18) wgf[t] = ldq(wgate, t, f32);        // w_gate [9,2] raw fp32

    if (t < 4) {  // b''[e][o] = sum_m b2[e][m]*Wout[m][o] + bout[o]
        int e = t >> 1, o = t & 1;
        float acc = ldq(bout, o, f32);
        for (int m = 0; m < 32; ++m)
            acc += ldq(b2, e * 32 + m, f32) * ldq(Wout, m * 2 + o, f32);
        bpp[t] = acc;
    }

    const int e = t >> 7;       // 256 threads -> (e, j)
    const int j = t & 127;
    float p0 = 0.f, p1 = 0.f;
    for (int m = 0; m < 32; ++m) {
        float w = ldq(W2, (e * 128 + j) * 32 + m, f32);
        p0 += w * ldq(Wout, m * 2 + 0, f32);
        p1 += w * ldq(Wout, m * 2 + 1, f32);
    }
    float* dst = wpack + e * 1536 + j * 12;
    #pragma unroll
    for (int d = 0; d < 9; ++d)
        dst[d] = ldq(W1, (e * 9 + d) * 128 + j, f32);
    dst[9]  = ldq(b1, e * 128 + j, f32);
    dst[10] = p0;
    dst[11] = p1;
}

// ---------------------------------------------------------------------------
// Main: 2048 tokens/block, 8/thread, grid 256 (1 block/CU). Stage weights
// (12KB) + x (72KB) in LDS. Gate 8 tokens, stable partition by expert
// (32 ballot-chunks in token order). Thread handles slots 8*tid..8*tid+7,
// all same expert (except <=1 straddler/block, fixed up after).
// Main loop: per j, 3 per-lane ds_read_b128 (record of own expert) + 8
// independent 9-FMA chains; 1-deep software rotate hides DS latency.
// DS 144 cyc/j/CU < VALU 192 cyc/j/CU -> VALU-bound.
// Results bounce through LDS (aliases xs, dead by then) -> coalesced.
// ---------------------------------------------------------------------------
__global__ __launch_bounds__(TPB, 1)
void moe_main(const void* __restrict__ xg,
              const int* __restrict__ flag,
              const float* __restrict__ wgf,
              const float* __restrict__ bpp,
              const float* __restrict__ wpack,
              unsigned int* __restrict__ cnt1,
              float2* __restrict__ out)
{
    __shared__ __align__(16) float xs[TOKB * 9];   // 73728 B
    __shared__ __align__(16) float wsm[3072];      // 12288 B (both experts)
    __shared__ unsigned short smap[TOKB];          // 4096 B
    __shared__ unsigned int wcnt[32];

    const int tid  = threadIdx.x;
    const int lane = tid & 63;
    const int wave = tid >> 6;

    const bool f32 = (*flag) != 0;

    // stage weights: 12 coalesced floats per thread
    #pragma unroll
    for (int i = 0; i < 12; ++i)
        wsm[tid + i * TPB] = wpack[tid + i * TPB];

    if (f32) {   // stage x as float4 (18 per thread, coalesced 16B/lane)
        const float4* xf4 = (const float4*)xg;
        float4* xsv = (float4*)xs;
        const int g4 = blockIdx.x * (TOKB * 9 / 4);
        #pragma unroll
        for (int i = 0; i < 18; ++i)
            xsv[tid + i * TPB] = xf4[g4 + tid + i * TPB];
    } else {
        const unsigned short* xu = (const unsigned short*)xg;
        const int gbase = blockIdx.x * (TOKB * 9);
        for (int i = tid; i < TOKB * 9; i += TPB)
            xs[i] = bf2f(xu[gbase + i]);
    }
    __syncthreads();

    // --- gate 8 tokens (tokens g*256 + tid); chains match accepted kernel ---
    bool e1g[8];
    unsigned long long balg[8];
    #pragma unroll
    for (int g = 0; g < 8; ++g) {
        float l0 = 0.f, l1 = 0.f;
        #pragma unroll
        for (int d = 0; d < 9; ++d) {
            float xv = xs[(g * 256 + tid) * 9 + d];
            l0 = fmaf(xv, wgf[d * 2 + 0], l0);
            l1 = fmaf(xv, wgf[d * 2 + 1], l1);
        }
        e1g[g] = l1 > l0;          // tie -> expert 0 (stable top_k)
        balg[g] = __ballot(e1g[g]);
        if (lane == 0) wcnt[g * 4 + wave] = (unsigned int)__popcll(balg[g]);
    }
    __syncthreads();

    // --- stable partition over 2048 tokens (chunk c = tok>>6 = token order) ---
    int pres[32]; int run = 0;
    #pragma unroll
    for (int c = 0; c < 32; ++c) { pres[c] = run; run += (int)wcnt[c]; }
    const int n1 = run;
    const int n0 = TOKB - n1;
    const unsigned long long below = (1ull << lane) - 1ull;
    #pragma unroll
    for (int g = 0; g < 8; ++g) {
        const int tok = g * 256 + tid;
        const int pr  = pres[g * 4 + wave] + (int)__popcll(balg[g] & below);
        const int slot = e1g[g] ? (n0 + pr) : (tok - pr);
        smap[slot] = (unsigned short)tok;
    }
    if (tid == 0) atomicAdd(cnt1, (unsigned int)n1);
    __syncthreads();

    // --- this thread processes slots 8*tid .. 8*tid+7 (one expert) ---
    const int s0 = tid * 8;
    int tkv[8];
    #pragma unroll
    for (int k = 0; k < 8; ++k) tkv[k] = (int)smap[s0 + k];
    float x[8][9];
    #pragma unroll
    for (int k = 0; k < 8; ++k)
        #pragma unroll
        for (int d = 0; d < 9; ++d) x[k][d] = xs[tkv[k] * 9 + d];

    // thread expert: straddler (s0 < n0 < s0+8) -> e0; its e1 slots fixed later
    const int ex = (s0 >= n0) ? 1 : 0;
    const float* wp = wsm + ex * 1536;
    float a0[8], a1[8];
    #pragma unroll
    for (int k = 0; k < 8; ++k) { a0[k] = bpp[ex * 2 + 0]; a1[k] = bpp[ex * 2 + 1]; }

    // main loop: 1-deep rotated DS prefetch; per j: 3 ds_read_b128 + 96 FMA
    const float4* q0 = (const float4*)wp;
    float4 A = q0[0], B = q0[1], C = q0[2];
    for (int j = 0; j < 128; ++j) {
        const int jn = (j + 1) & 127;                 // wraps to 0, harmless
        const float4* qn = (const float4*)(wp + jn * 12);
        const float4 An = qn[0], Bn = qn[1], Cn = qn[2];
        #pragma unroll
        for (int k = 0; k < 8; ++k) {
            float h = C.y;
            h = fmaf(x[k][0], A.x, h); h = fmaf(x[k][1], A.y, h);
            h = fmaf(x[k][2], A.z, h); h = fmaf(x[k][3], A.w, h);
            h = fmaf(x[k][4], B.x, h); h = fmaf(x[k][5], B.y, h);
            h = fmaf(x[k][6], B.z, h); h = fmaf(x[k][7], B.w, h);
            h = fmaf(x[k][8], C.x, h);
            h = fmaxf(h, 0.f);
            a0[k] = fmaf(h, C.z, a0[k]);
            a1[k] = fmaf(h, C.w, a1[k]);
        }
        A = An; B = Bn; C = Cn;
    }

    // --- fixup: straddler's slots n0..n0+nw-1 were computed with e0; lanes
    //     0..nw-1 (wave 0) recompute them with e1 (same per-token chain) ---
    const int nw = (n0 & 7) ? (8 - (n0 & 7)) : 0;
    float fx0 = 0.f, fx1 = 0.f; int ftk = 0;
    if (tid < nw) {
        ftk = (int)smap[n0 + tid];
        float xr[9];
        #pragma unroll
        for (int d = 0; d < 9; ++d) xr[d] = xs[ftk * 9 + d];
        fx0 = bpp[2]; fx1 = bpp[3];
        const float* wq = wsm + 1536;
        for (int j = 0; j < 128; ++j) {
            const float4* q = (const float4*)(wq + j * 12);
            const float4 Af = q[0], Bf = q[1], Cf = q[2];
            float h = Cf.y;
            h = fmaf(xr[0], Af.x, h); h = fmaf(xr[1], Af.y, h);
            h = fmaf(xr[2], Af.z, h); h = fmaf(xr[3], Af.w, h);
            h = fmaf(xr[4], Bf.x, h); h = fmaf(xr[5], Bf.y, h);
            h = fmaf(xr[6], Bf.z, h); h = fmaf(xr[7], Bf.w, h);
            h = fmaf(xr[8], Cf.x, h);
            h = fmaxf(h, 0.f);
            fx0 = fmaf(h, Cf.z, fx0);
            fx1 = fmaf(h, Cf.w, fx1);
        }
    }

    // --- bounce through LDS to token order (ob aliases xs: xs dead now) ---
    __syncthreads();                        // all xs/wsm reads complete
    float2* ob = (float2*)xs;               // 2048 float2 = 16384 B < xs
    #pragma unroll
    for (int k = 0; k < 8; ++k)
        ob[tkv[k]] = make_float2(a0[k], a1[k]);
    __syncthreads();
    if (tid < nw) ob[ftk] = make_float2(fx0, fx1);   // overwrite wrong-expert
    __syncthreads();
    const int obase = blockIdx.x * TOKB;
    #pragma unroll
    for (int g = 0; g < 8; ++g)
        out[obase + g * 256 + tid] = ob[g * 256 + tid];
}

// Loss: gates one-hot value-1.0 -> importance == load == counts.
// cv^2 ddof=1: var=(c0-c1)^2/2, mean=N/2; loss = 0.01*2*cv^2 (~1e-9).
__global__ void finalize_kernel(const unsigned int* __restrict__ cnt1,
                                float* __restrict__ loss_out)
{
    double c1 = (double)(*cnt1);
    double c0 = (double)NTOK - c1;
    double diff = c0 - c1;
    double mean = (double)NTOK * 0.5;
    double var  = 0.5 * diff * diff;
    double cv2  = var / (mean * mean + 1e-10);
    *loss_out = (float)(0.02 * cv2);
}

extern "C" void kernel_launch(void* const* d_in, const int* in_sizes, int n_in,
                              void* d_out, int out_size, void* d_ws, size_t ws_size,
                              hipStream_t stream) {
    const void* num_prop = d_in[0]; // [N,9] fp32
    // d_in[1] = cat_prop (unused)
    const void* w_gate   = d_in[2]; // [9,2]
    const void* W1       = d_in[3]; // [2,9,128]
    const void* b1       = d_in[4]; // [2,128]
    const void* W2       = d_in[5]; // [2,128,32]
    const void* b2       = d_in[6]; // [2,32]
    const void* Wout     = d_in[7]; // [32,2]
    const void* bout     = d_in[8]; // [2]
    // d_in[9] = k (==1)

    char* ws = (char*)d_ws;
    unsigned int* cnt1 = (unsigned int*)ws;          // @0
    int* flag          = (int*)(ws + 8);             // @8
    float* bpp         = (float*)(ws + 16);          // 4 f
    float* wgf         = (float*)(ws + 64);          // 18 f
    float* wpack       = (float*)(ws + 192);         // 3072 f (expert-major)

    float*  outf = (float*)d_out;                    // FP32: N*2 + loss
    float2* out2 = (float2*)d_out;

    hipLaunchKernelGGL(prep_kernel, dim3(1), dim3(256), 0, stream,
                       num_prop, w_gate, W1, b1, W2, b2, Wout, bout,
                       cnt1, flag, bpp, wgf, wpack);
    hipLaunchKernelGGL(moe_main, dim3(NBLK), dim3(TPB), 0, stream,
                       num_prop, flag, wgf, bpp, wpack, cnt1, out2);
    hipLaunchKernelGGL(finalize_kernel, dim3(1), dim3(1), 0, stream,
                       cnt1, outf + (size_t)NTOK * 2);
}

// Round 9
// 139.698 us; speedup vs baseline: 1.0013x; 1.0013x over previous
//
#include <hip/hip_runtime.h>

// N=524288, D=9, E=2, H=128, M=32, O=2, K=1.
// LAYOUT (confirmed R6): d_in fp32, d_out FP32 (N*2 outputs + 1 loss).
// NUMERICS: pure fp32; per-token fmaf chains identical to accepted kernel.
//
// R9 = R8's K=8 compute loop + the occupancy it lacked.
// Validated models: DS b128 ~12cyc/wave-instr even broadcast (R5 fit);
// v_readlane ~26cyc (R7 fit) banned; SMEM unpipelined (R0-R4) banned;
// R8: 1 wave/SIMD exposes all latency (975 cyc/j wall vs 220 issue).
// Fix: DELETE the 72KB x-staging LDS. Gate reads x from global (coalesced
// at line granularity); permuted post-partition read re-fetches from
// global (block window 72KB x 32 blocks/XCD = 2.3MB < 4MB L2 -> L2-hit).
// LDS = 12KB weights + 4KB smap + 16KB out-bounce = 33KB ->
// __launch_bounds__(256,3): 3 blocks/CU = 3 waves/SIMD TLP.
// DS floor 7.7us, VALU floor 10.2us -> moe ~15-19us predicted.
#define NTOK 524288
#define TPB  256
#define TOKB 2048             // tokens per block (8 per thread)
#define NBLK (NTOK / TOKB)    // 256

__device__ __forceinline__ float bf2f(unsigned short u) {
    union { unsigned int i; float f; } v;
    v.i = ((unsigned int)u) << 16;
    return v.f;
}

// input load: raw fp32 (bf16-buffer fallback kept purely as safety)
__device__ __forceinline__ float ldq(const void* p, int i, bool f32) {
    if (f32) return ((const float*)p)[i];
    return bf2f(((const unsigned short*)p)[i]);
}

// ---------------------------------------------------------------------------
// Prep: detect buffer dtype (parallel probe), zero counter, stage w_gate,
// fold W2@Wout (+ b2@Wout + bout), pack per-hidden-unit weights.
// wpack layout (expert-major): wpack[e*1536 + j*12 + {0..8:W1col, 9:b1,
// 10..11:W2'}] — 48B records, 16B-aligned.
// ---------------------------------------------------------------------------
__global__ void prep_kernel(const void* __restrict__ num_prop,
                            const void* __restrict__ wgate,
                            const void* __restrict__ W1,
                            const void* __restrict__ b1,
                            const void* __restrict__ W2,
                            const void* __restrict__ b2,
                            const void* __restrict__ Wout,
                            const void* __restrict__ bout,
                            unsigned int* __restrict__ cnt1,
                            int* __restrict__ flag,
                            float* __restrict__ bpp,
                            float* __restrict__ wgf,
                            float* __restrict__ wpack)
{
    __shared__ unsigned int bad;
    __shared__ int sflag;
    const int t = threadIdx.x;
    if (t == 0) { bad = 0u; *cnt1 = 0u; }
    __syncthreads();
    if (t < 72) {   // parallel dtype probe
        const unsigned short* u = (const unsigned short*)num_prop;
        int e = (u[t] >> 7) & 0xFF;
        if (e < 64 || e > 191) atomicOr(&bad, 1u);
    }
    __syncthreads();
    if (t == 0) { sflag = (int)bad; *flag = (int)bad; }
    __syncthreads();
    const bool f32 = (sflag != 0);

    if (t < 18) wgf[t] = ldq(wgate, t, f32);        // w_gate [9,2] raw fp32

    if (t < 4) {  // b''[e][o] = sum_m b2[e][m]*Wout[m][o] + bout[o]
        int e = t >> 1, o = t & 1;
        float acc = ldq(bout, o, f32);
        for (int m = 0; m < 32; ++m)
            acc += ldq(b2, e * 32 + m, f32) * ldq(Wout, m * 2 + o, f32);
        bpp[t] = acc;
    }

    const int e = t >> 7;       // 256 threads -> (e, j)
    const int j = t & 127;
    float p0 = 0.f, p1 = 0.f;
    for (int m = 0; m < 32; ++m) {
        float w = ldq(W2, (e * 128 + j) * 32 + m, f32);
        p0 += w * ldq(Wout, m * 2 + 0, f32);
        p1 += w * ldq(Wout, m * 2 + 1, f32);
    }
    float* dst = wpack + e * 1536 + j * 12;
    #pragma unroll
    for (int d = 0; d < 9; ++d)
        dst[d] = ldq(W1, (e * 9 + d) * 128 + j, f32);
    dst[9]  = ldq(b1, e * 128 + j, f32);
    dst[10] = p0;
    dst[11] = p1;
}

// ---------------------------------------------------------------------------
// Main: 2048 tokens/block, 8/thread, grid 256, 3 blocks/CU. Weights (12KB)
// in LDS; x NOT staged (gate + permuted reads from global, 2nd read L2-hot).
// Gate 8 tokens, stable partition by expert (32 ballot-chunks in token
// order). Thread handles slots 8*tid..8*tid+7, one expert each (<=1
// straddler/block fixed up after). Main loop: per j, 3 per-lane broadcast
// ds_read_b128 (1-deep rotate) + 8 independent 9-FMA chains.
// Results bounce through 16KB LDS to token order -> coalesced stores.
// ---------------------------------------------------------------------------
__global__ __launch_bounds__(TPB, 3)
void moe_main(const void* __restrict__ xg,
              const int* __restrict__ flag,
              const float* __restrict__ wgf,
              const float* __restrict__ bpp,
              const float* __restrict__ wpack,
              unsigned int* __restrict__ cnt1,
              float2* __restrict__ out)
{
    __shared__ __align__(16) float wsm[3072];      // 12288 B (both experts)
    __shared__ unsigned short smap[TOKB];          // 4096 B
    __shared__ float2 ob[TOKB];                    // 16384 B
    __shared__ unsigned int wcnt[32];

    const int tid  = threadIdx.x;
    const int lane = tid & 63;
    const int wave = tid >> 6;

    // stage weights: 12 coalesced floats per thread
    #pragma unroll
    for (int i = 0; i < 12; ++i)
        wsm[tid + i * TPB] = wpack[tid + i * TPB];
    __syncthreads();

    const bool f32 = (*flag) != 0;
    const int tbase = blockIdx.x * TOKB;

    if (!f32) {
        // bf16 fallback: correct-but-slow (never triggers; inputs are fp32).
        const unsigned short* xu = (const unsigned short*)xg;
        for (int g = 0; g < 8; ++g) {
            const int tok = g * 256 + tid;
            float xr[9];
            #pragma unroll
            for (int d = 0; d < 9; ++d)
                xr[d] = bf2f(xu[(size_t)(tbase + tok) * 9 + d]);
            float l0 = 0.f, l1 = 0.f;
            #pragma unroll
            for (int d = 0; d < 9; ++d) {
                l0 = fmaf(xr[d], wgf[d * 2 + 0], l0);
                l1 = fmaf(xr[d], wgf[d * 2 + 1], l1);
            }
            const bool e1 = l1 > l0;
            unsigned long long bal = __ballot(e1);
            if (lane == 0) atomicAdd(cnt1, (unsigned int)__popcll(bal));
            float a00 = bpp[0], a01 = bpp[1], a10 = bpp[2], a11 = bpp[3];
            for (int j = 0; j < 128; ++j) {
                const float* r0 = wsm + j * 12;
                const float* r1 = wsm + 1536 + j * 12;
                float h0 = r0[9], h1 = r1[9];
                #pragma unroll
                for (int d = 0; d < 9; ++d) {
                    h0 = fmaf(xr[d], r0[d], h0);
                    h1 = fmaf(xr[d], r1[d], h1);
                }
                h0 = fmaxf(h0, 0.f); h1 = fmaxf(h1, 0.f);
                a00 = fmaf(h0, r0[10], a00); a01 = fmaf(h0, r0[11], a01);
                a10 = fmaf(h1, r1[10], a10); a11 = fmaf(h1, r1[11], a11);
            }
            out[tbase + tok] = make_float2(e1 ? a10 : a00, e1 ? a11 : a01);
        }
        return;
    }

    const float* xf = (const float*)xg;
    const size_t rb = (size_t)tbase * 9;

    // --- gate 8 tokens from global (9 dwords/token; lanes = adjacent rows) ---
    bool e1g[8];
    unsigned long long balg[8];
    #pragma unroll
    for (int g = 0; g < 8; ++g) {
        const int tok = g * 256 + tid;
        float l0 = 0.f, l1 = 0.f;
        #pragma unroll
        for (int d = 0; d < 9; ++d) {
            const float xv = xf[rb + (size_t)tok * 9 + d];
            l0 = fmaf(xv, wgf[d * 2 + 0], l0);
            l1 = fmaf(xv, wgf[d * 2 + 1], l1);
        }
        e1g[g] = l1 > l0;          // tie -> expert 0 (stable top_k)
        balg[g] = __ballot(e1g[g]);
        if (lane == 0) wcnt[g * 4 + wave] = (unsigned int)__popcll(balg[g]);
    }
    __syncthreads();

    // --- stable partition over 2048 tokens (chunk c = tok>>6 = token order) ---
    int pres[32]; int run = 0;
    #pragma unroll
    for (int c = 0; c < 32; ++c) { pres[c] = run; run += (int)wcnt[c]; }
    const int n1 = run;
    const int n0 = TOKB - n1;
    const unsigned long long below = (1ull << lane) - 1ull;
    #pragma unroll
    for (int g = 0; g < 8; ++g) {
        const int tok = g * 256 + tid;
        const int pr  = pres[g * 4 + wave] + (int)__popcll(balg[g] & below);
        const int slot = e1g[g] ? (n0 + pr) : (tok - pr);
        smap[slot] = (unsigned short)tok;
    }
    if (tid == 0) atomicAdd(cnt1, (unsigned int)n1);
    __syncthreads();

    // --- this thread processes slots 8*tid .. 8*tid+7 (one expert) ---
    const int s0 = tid * 8;
    int tkv[8];
    #pragma unroll
    for (int k = 0; k < 8; ++k) tkv[k] = (int)smap[s0 + k];
    // permuted x fetch from global (block window is L2/L1-hot after gate)
    float x[8][9];
    #pragma unroll
    for (int k = 0; k < 8; ++k) {
        const size_t rk = rb + (size_t)tkv[k] * 9;
        #pragma unroll
        for (int d = 0; d < 9; ++d) x[k][d] = xf[rk + d];
    }

    // thread expert: straddler (s0 < n0 < s0+8) -> e0; its e1 slots fixed later
    const int ex = (s0 >= n0) ? 1 : 0;
    const float* wp = wsm + ex * 1536;
    float a0[8], a1[8];
    #pragma unroll
    for (int k = 0; k < 8; ++k) { a0[k] = bpp[ex * 2 + 0]; a1[k] = bpp[ex * 2 + 1]; }

    // main loop: 1-deep rotated DS prefetch; per j: 3 ds_read_b128 + 96 FMA
    const float4* q0 = (const float4*)wp;
    float4 A = q0[0], B = q0[1], C = q0[2];
    for (int j = 0; j < 128; ++j) {
        const int jn = (j + 1) & 127;                 // wraps to 0, harmless
        const float4* qn = (const float4*)(wp + jn * 12);
        const float4 An = qn[0], Bn = qn[1], Cn = qn[2];
        #pragma unroll
        for (int k = 0; k < 8; ++k) {
            float h = C.y;
            h = fmaf(x[k][0], A.x, h); h = fmaf(x[k][1], A.y, h);
            h = fmaf(x[k][2], A.z, h); h = fmaf(x[k][3], A.w, h);
            h = fmaf(x[k][4], B.x, h); h = fmaf(x[k][5], B.y, h);
            h = fmaf(x[k][6], B.z, h); h = fmaf(x[k][7], B.w, h);
            h = fmaf(x[k][8], C.x, h);
            h = fmaxf(h, 0.f);
            a0[k] = fmaf(h, C.z, a0[k]);
            a1[k] = fmaf(h, C.w, a1[k]);
        }
        A = An; B = Bn; C = Cn;
    }

    // --- fixup: straddler's slots n0..n0+nw-1 were computed with e0; lanes
    //     0..nw-1 recompute them with e1 (same per-token chain, bit-exact) ---
    const int nw = (n0 & 7) ? (8 - (n0 & 7)) : 0;
    float fx0 = 0.f, fx1 = 0.f; int ftk = 0;
    if (tid < nw) {
        ftk = (int)smap[n0 + tid];
        float xr[9];
        const size_t rk = rb + (size_t)ftk * 9;
        #pragma unroll
        for (int d = 0; d < 9; ++d) xr[d] = xf[rk + d];
        fx0 = bpp[2]; fx1 = bpp[3];
        const float* wq = wsm + 1536;
        for (int j = 0; j < 128; ++j) {
            const float4* q = (const float4*)(wq + j * 12);
            const float4 Af = q[0], Bf = q[1], Cf = q[2];
            float h = Cf.y;
            h = fmaf(xr[0], Af.x, h); h = fmaf(xr[1], Af.y, h);
            h = fmaf(xr[2], Af.z, h); h = fmaf(xr[3], Af.w, h);
            h = fmaf(xr[4], Bf.x, h); h = fmaf(xr[5], Bf.y, h);
            h = fmaf(xr[6], Bf.z, h); h = fmaf(xr[7], Bf.w, h);
            h = fmaf(xr[8], Cf.x, h);
            h = fmaxf(h, 0.f);
            fx0 = fmaf(h, Cf.z, fx0);
            fx1 = fmaf(h, Cf.w, fx1);
        }
    }

    // --- bounce through LDS to token order -> coalesced float2 stores ---
    #pragma unroll
    for (int k = 0; k < 8; ++k)
        ob[tkv[k]] = make_float2(a0[k], a1[k]);
    __syncthreads();
    if (tid < nw) ob[ftk] = make_float2(fx0, fx1);   // overwrite wrong-expert
    __syncthreads();
    #pragma unroll
    for (int g = 0; g < 8; ++g)
        out[tbase + g * 256 + tid] = ob[g * 256 + tid];
}

// Loss: gates one-hot value-1.0 -> importance == load == counts.
// cv^2 ddof=1: var=(c0-c1)^2/2, mean=N/2; loss = 0.01*2*cv^2 (~1e-9).
__global__ void finalize_kernel(const unsigned int* __restrict__ cnt1,
                                float* __restrict__ loss_out)
{
    double c1 = (double)(*cnt1);
    double c0 = (double)NTOK - c1;
    double diff = c0 - c1;
    double mean = (double)NTOK * 0.5;
    double var  = 0.5 * diff * diff;
    double cv2  = var / (mean * mean + 1e-10);
    *loss_out = (float)(0.02 * cv2);
}

extern "C" void kernel_launch(void* const* d_in, const int* in_sizes, int n_in,
                              void* d_out, int out_size, void* d_ws, size_t ws_size,
                              hipStream_t stream) {
    const void* num_prop = d_in[0]; // [N,9] fp32
    // d_in[1] = cat_prop (unused)
    const void* w_gate   = d_in[2]; // [9,2]
    const void* W1       = d_in[3]; // [2,9,128]
    const void* b1       = d_in[4]; // [2,128]
    const void* W2       = d_in[5]; // [2,128,32]
    const void* b2       = d_in[6]; // [2,32]
    const void* Wout     = d_in[7]; // [32,2]
    const void* bout     = d_in[8]; // [2]
    // d_in[9] = k (==1)

    char* ws = (char*)d_ws;
    unsigned int* cnt1 = (unsigned int*)ws;          // @0
    int* flag          = (int*)(ws + 8);             // @8
    float* bpp         = (float*)(ws + 16);          // 4 f
    float* wgf         = (float*)(ws + 64);          // 18 f
    float* wpack       = (float*)(ws + 192);         // 3072 f (expert-major)

    float*  outf = (float*)d_out;                    // FP32: N*2 + loss
    float2* out2 = (float2*)d_out;

    hipLaunchKernelGGL(prep_kernel, dim3(1), dim3(256), 0, stream,
                       num_prop, w_gate, W1, b1, W2, b2, Wout, bout,
                       cnt1, flag, bpp, wgf, wpack);
    hipLaunchKernelGGL(moe_main, dim3(NBLK), dim3(TPB), 0, stream,
                       num_prop, flag, wgf, bpp, wpack, cnt1, out2);
    hipLaunchKernelGGL(finalize_kernel, dim3(1), dim3(1), 0, stream,
                       cnt1, outf + (size_t)NTOK * 2);
}

// Round 10
// 137.775 us; speedup vs baseline: 1.0153x; 1.0140x over previous
//
#include <hip/hip_runtime.h>

// N=524288, D=9, E=2, H=128, M=32, O=2, K=1.
// LAYOUT (confirmed R6): d_in fp32, d_out FP32 (N*2 outputs + 1 loss).
// NUMERICS: pure fp32; per-token fmaf chains identical to accepted kernel.
//
// R10: K=4 — the middle of the (now fully measured) K x TLP tradeoff.
// Invariant: K * waves/SIMD = 8 (one pass over N). Measured endpoints:
//   K=2, 4 w/SIMD: DS-broadcast-bound 3x  -> 38.5us (R5, model-exact)
//   K=8, 1 w/SIMD: latency-exposed        -> 52us   (R8/R9; R9 grid=256
//        could never give >1 block/CU - launch_bounds can't add blocks)
// K=4, 2 w/SIMD: DS floor = 8 waves/CU x 128j x 36cyc = 15.4us with a
// second wave/SIMD to hide DS latency; VALU floor 10.2us underneath.
// Structure = R9 (validated: x unstaged, FETCH flat, conflicts low):
// weights 12KB LDS (3 broadcast ds_read_b128/j, 1-deep rotate), stable
// partition, straddler fixup, bit-exact chains. LDS 22.6KB, lb(256,2).
#define NTOK 524288
#define TPB  256
#define TOKB 1024             // tokens per block (4 per thread)
#define NBLK (NTOK / TOKB)    // 512 -> 2 blocks/CU

__device__ __forceinline__ float bf2f(unsigned short u) {
    union { unsigned int i; float f; } v;
    v.i = ((unsigned int)u) << 16;
    return v.f;
}

// input load: raw fp32 (bf16-buffer fallback kept purely as safety)
__device__ __forceinline__ float ldq(const void* p, int i, bool f32) {
    if (f32) return ((const float*)p)[i];
    return bf2f(((const unsigned short*)p)[i]);
}

// ---------------------------------------------------------------------------
// Prep: detect buffer dtype (parallel probe), zero counter, stage w_gate,
// fold W2@Wout (+ b2@Wout + bout), pack per-hidden-unit weights.
// wpack layout (expert-major): wpack[e*1536 + j*12 + {0..8:W1col, 9:b1,
// 10..11:W2'}] — 48B records, 16B-aligned.
// ---------------------------------------------------------------------------
__global__ void prep_kernel(const void* __restrict__ num_prop,
                            const void* __restrict__ wgate,
                            const void* __restrict__ W1,
                            const void* __restrict__ b1,
                            const void* __restrict__ W2,
                            const void* __restrict__ b2,
                            const void* __restrict__ Wout,
                            const void* __restrict__ bout,
                            unsigned int* __restrict__ cnt1,
                            int* __restrict__ flag,
                            float* __restrict__ bpp,
                            float* __restrict__ wgf,
                            float* __restrict__ wpack)
{
    __shared__ unsigned int bad;
    __shared__ int sflag;
    const int t = threadIdx.x;
    if (t == 0) { bad = 0u; *cnt1 = 0u; }
    __syncthreads();
    if (t < 72) {   // parallel dtype probe
        const unsigned short* u = (const unsigned short*)num_prop;
        int e = (u[t] >> 7) & 0xFF;
        if (e < 64 || e > 191) atomicOr(&bad, 1u);
    }
    __syncthreads();
    if (t == 0) { sflag = (int)bad; *flag = (int)bad; }
    __syncthreads();
    const bool f32 = (sflag != 0);

    if (t < 18) wgf[t] = ldq(wgate, t, f32);        // w_gate [9,2] raw fp32

    if (t < 4) {  // b''[e][o] = sum_m b2[e][m]*Wout[m][o] + bout[o]
        int e = t >> 1, o = t & 1;
        float acc = ldq(bout, o, f32);
        for (int m = 0; m < 32; ++m)
            acc += ldq(b2, e * 32 + m, f32) * ldq(Wout, m * 2 + o, f32);
        bpp[t] = acc;
    }

    const int e = t >> 7;       // 256 threads -> (e, j)
    const int j = t & 127;
    float p0 = 0.f, p1 = 0.f;
    for (int m = 0; m < 32; ++m) {
        float w = ldq(W2, (e * 128 + j) * 32 + m, f32);
        p0 += w * ldq(Wout, m * 2 + 0, f32);
        p1 += w * ldq(Wout, m * 2 + 1, f32);
    }
    float* dst = wpack + e * 1536 + j * 12;
    #pragma unroll
    for (int d = 0; d < 9; ++d)
        dst[d] = ldq(W1, (e * 9 + d) * 128 + j, f32);
    dst[9]  = ldq(b1, e * 128 + j, f32);
    dst[10] = p0;
    dst[11] = p1;
}

// ---------------------------------------------------------------------------
// Main: 1024 tokens/block, 4/thread, grid 512 (2 blocks/CU, 2 waves/SIMD).
// Weights (12KB) in LDS; x NOT staged (gate + permuted reads from global,
// 2nd read L1/L2-hot — validated R9: FETCH flat). Gate 4 tokens, stable
// partition by expert (16 ballot-chunks = token order). Thread handles
// slots 4*tid..4*tid+3, one expert (<=1 straddler/block fixed up after).
// Main loop: per j, 3 per-lane broadcast ds_read_b128 (1-deep rotate) +
// 4 independent 9-FMA chains. Results bounce through 8KB LDS -> coalesced.
// ---------------------------------------------------------------------------
__global__ __launch_bounds__(TPB, 2)
void moe_main(const void* __restrict__ xg,
              const int* __restrict__ flag,
              const float* __restrict__ wgf,
              const float* __restrict__ bpp,
              const float* __restrict__ wpack,
              unsigned int* __restrict__ cnt1,
              float2* __restrict__ out)
{
    __shared__ __align__(16) float wsm[3072];      // 12288 B (both experts)
    __shared__ unsigned short smap[TOKB];          // 2048 B
    __shared__ float2 ob[TOKB];                    // 8192 B
    __shared__ unsigned int wcnt[16];

    const int tid  = threadIdx.x;
    const int lane = tid & 63;
    const int wave = tid >> 6;

    // stage weights: 12 coalesced floats per thread
    #pragma unroll
    for (int i = 0; i < 12; ++i)
        wsm[tid + i * TPB] = wpack[tid + i * TPB];
    __syncthreads();

    const bool f32 = (*flag) != 0;
    const int tbase = blockIdx.x * TOKB;

    if (!f32) {
        // bf16 fallback: correct-but-slow (never triggers; inputs are fp32).
        const unsigned short* xu = (const unsigned short*)xg;
        for (int g = 0; g < 4; ++g) {
            const int tok = g * 256 + tid;
            float xr[9];
            #pragma unroll
            for (int d = 0; d < 9; ++d)
                xr[d] = bf2f(xu[(size_t)(tbase + tok) * 9 + d]);
            float l0 = 0.f, l1 = 0.f;
            #pragma unroll
            for (int d = 0; d < 9; ++d) {
                l0 = fmaf(xr[d], wgf[d * 2 + 0], l0);
                l1 = fmaf(xr[d], wgf[d * 2 + 1], l1);
            }
            const bool e1 = l1 > l0;
            unsigned long long bal = __ballot(e1);
            if (lane == 0) atomicAdd(cnt1, (unsigned int)__popcll(bal));
            float a00 = bpp[0], a01 = bpp[1], a10 = bpp[2], a11 = bpp[3];
            for (int j = 0; j < 128; ++j) {
                const float* r0 = wsm + j * 12;
                const float* r1 = wsm + 1536 + j * 12;
                float h0 = r0[9], h1 = r1[9];
                #pragma unroll
                for (int d = 0; d < 9; ++d) {
                    h0 = fmaf(xr[d], r0[d], h0);
                    h1 = fmaf(xr[d], r1[d], h1);
                }
                h0 = fmaxf(h0, 0.f); h1 = fmaxf(h1, 0.f);
                a00 = fmaf(h0, r0[10], a00); a01 = fmaf(h0, r0[11], a01);
                a10 = fmaf(h1, r1[10], a10); a11 = fmaf(h1, r1[11], a11);
            }
            out[tbase + tok] = make_float2(e1 ? a10 : a00, e1 ? a11 : a01);
        }
        return;
    }

    const float* xf = (const float*)xg;
    const size_t rb = (size_t)tbase * 9;

    // --- gate 4 tokens from global (9 dwords/token; lanes = adjacent rows) ---
    bool e1g[4];
    unsigned long long balg[4];
    #pragma unroll
    for (int g = 0; g < 4; ++g) {
        const int tok = g * 256 + tid;
        float l0 = 0.f, l1 = 0.f;
        #pragma unroll
        for (int d = 0; d < 9; ++d) {
            const float xv = xf[rb + (size_t)tok * 9 + d];
            l0 = fmaf(xv, wgf[d * 2 + 0], l0);
            l1 = fmaf(xv, wgf[d * 2 + 1], l1);
        }
        e1g[g] = l1 > l0;          // tie -> expert 0 (stable top_k)
        balg[g] = __ballot(e1g[g]);
        if (lane == 0) wcnt[g * 4 + wave] = (unsigned int)__popcll(balg[g]);
    }
    __syncthreads();

    // --- stable partition over 1024 tokens (chunk c = tok>>6 = token order) ---
    int pres[16]; int run = 0;
    #pragma unroll
    for (int c = 0; c < 16; ++c) { pres[c] = run; run += (int)wcnt[c]; }
    const int n1 = run;
    const int n0 = TOKB - n1;
    const unsigned long long below = (1ull << lane) - 1ull;
    #pragma unroll
    for (int g = 0; g < 4; ++g) {
        const int tok = g * 256 + tid;
        const int pr  = pres[g * 4 + wave] + (int)__popcll(balg[g] & below);
        const int slot = e1g[g] ? (n0 + pr) : (tok - pr);
        smap[slot] = (unsigned short)tok;
    }
    if (tid == 0) atomicAdd(cnt1, (unsigned int)n1);
    __syncthreads();

    // --- this thread processes slots 4*tid .. 4*tid+3 (one expert) ---
    const int s0 = tid * 4;
    int tkv[4];
    #pragma unroll
    for (int k = 0; k < 4; ++k) tkv[k] = (int)smap[s0 + k];
    // permuted x fetch from global (block window is L1/L2-hot after gate)
    float x[4][9];
    #pragma unroll
    for (int k = 0; k < 4; ++k) {
        const size_t rk = rb + (size_t)tkv[k] * 9;
        #pragma unroll
        for (int d = 0; d < 9; ++d) x[k][d] = xf[rk + d];
    }

    // thread expert: straddler (s0 < n0 < s0+4) -> e0; its e1 slots fixed later
    const int ex = (s0 >= n0) ? 1 : 0;
    const float* wp = wsm + ex * 1536;
    float a0[4], a1[4];
    #pragma unroll
    for (int k = 0; k < 4; ++k) { a0[k] = bpp[ex * 2 + 0]; a1[k] = bpp[ex * 2 + 1]; }

    // main loop: 1-deep rotated DS prefetch; per j: 3 ds_read_b128 + 48 FMA
    const float4* q0 = (const float4*)wp;
    float4 A = q0[0], B = q0[1], C = q0[2];
    for (int j = 0; j < 128; ++j) {
        const int jn = (j + 1) & 127;                 // wraps to 0, harmless
        const float4* qn = (const float4*)(wp + jn * 12);
        const float4 An = qn[0], Bn = qn[1], Cn = qn[2];
        #pragma unroll
        for (int k = 0; k < 4; ++k) {
            float h = C.y;
            h = fmaf(x[k][0], A.x, h); h = fmaf(x[k][1], A.y, h);
            h = fmaf(x[k][2], A.z, h); h = fmaf(x[k][3], A.w, h);
            h = fmaf(x[k][4], B.x, h); h = fmaf(x[k][5], B.y, h);
            h = fmaf(x[k][6], B.z, h); h = fmaf(x[k][7], B.w, h);
            h = fmaf(x[k][8], C.x, h);
            h = fmaxf(h, 0.f);
            a0[k] = fmaf(h, C.z, a0[k]);
            a1[k] = fmaf(h, C.w, a1[k]);
        }
        A = An; B = Bn; C = Cn;
    }

    // --- fixup: straddler's slots n0..n0+nw-1 were computed with e0; lanes
    //     0..nw-1 recompute them with e1 (same per-token chain, bit-exact) ---
    const int nw = (4 - (n0 & 3)) & 3;
    float fx0 = 0.f, fx1 = 0.f; int ftk = 0;
    if (tid < nw) {
        ftk = (int)smap[n0 + tid];
        float xr[9];
        const size_t rk = rb + (size_t)ftk * 9;
        #pragma unroll
        for (int d = 0; d < 9; ++d) xr[d] = xf[rk + d];
        fx0 = bpp[2]; fx1 = bpp[3];
        const float* wq = wsm + 1536;
        for (int j = 0; j < 128; ++j) {
            const float4* q = (const float4*)(wq + j * 12);
            const float4 Af = q[0], Bf = q[1], Cf = q[2];
            float h = Cf.y;
            h = fmaf(xr[0], Af.x, h); h = fmaf(xr[1], Af.y, h);
            h = fmaf(xr[2], Af.z, h); h = fmaf(xr[3], Af.w, h);
            h = fmaf(xr[4], Bf.x, h); h = fmaf(xr[5], Bf.y, h);
            h = fmaf(xr[6], Bf.z, h); h = fmaf(xr[7], Bf.w, h);
            h = fmaf(xr[8], Cf.x, h);
            h = fmaxf(h, 0.f);
            fx0 = fmaf(h, Cf.z, fx0);
            fx1 = fmaf(h, Cf.w, fx1);
        }
    }

    // --- bounce through LDS to token order -> coalesced float2 stores ---
    #pragma unroll
    for (int k = 0; k < 4; ++k)
        ob[tkv[k]] = make_float2(a0[k], a1[k]);
    __syncthreads();
    if (tid < nw) ob[ftk] = make_float2(fx0, fx1);   // overwrite wrong-expert
    __syncthreads();
    #pragma unroll
    for (int g = 0; g < 4; ++g)
        out[tbase + g * 256 + tid] = ob[g * 256 + tid];
}

// Loss: gates one-hot value-1.0 -> importance == load == counts.
// cv^2 ddof=1: var=(c0-c1)^2/2, mean=N/2; loss = 0.01*2*cv^2 (~1e-9).
__global__ void finalize_kernel(const unsigned int* __restrict__ cnt1,
                                float* __restrict__ loss_out)
{
    double c1 = (double)(*cnt1);
    double c0 = (double)NTOK - c1;
    double diff = c0 - c1;
    double mean = (double)NTOK * 0.5;
    double var  = 0.5 * diff * diff;
    double cv2  = var / (mean * mean + 1e-10);
    *loss_out = (float)(0.02 * cv2);
}

extern "C" void kernel_launch(void* const* d_in, const int* in_sizes, int n_in,
                              void* d_out, int out_size, void* d_ws, size_t ws_size,
                              hipStream_t stream) {
    const void* num_prop = d_in[0]; // [N,9] fp32
    // d_in[1] = cat_prop (unused)
    const void* w_gate   = d_in[2]; // [9,2]
    const void* W1       = d_in[3]; // [2,9,128]
    const void* b1       = d_in[4]; // [2,128]
    const void* W2       = d_in[5]; // [2,128,32]
    const void* b2       = d_in[6]; // [2,32]
    const void* Wout     = d_in[7]; // [32,2]
    const void* bout     = d_in[8]; // [2]
    // d_in[9] = k (==1)

    char* ws = (char*)d_ws;
    unsigned int* cnt1 = (unsigned int*)ws;          // @0
    int* flag          = (int*)(ws + 8);             // @8
    float* bpp         = (float*)(ws + 16);          // 4 f
    float* wgf         = (float*)(ws + 64);          // 18 f
    float* wpack       = (float*)(ws + 192);         // 3072 f (expert-major)

    float*  outf = (float*)d_out;                    // FP32: N*2 + loss
    float2* out2 = (float2*)d_out;

    hipLaunchKernelGGL(prep_kernel, dim3(1), dim3(256), 0, stream,
                       num_prop, w_gate, W1, b1, W2, b2, Wout, bout,
                       cnt1, flag, bpp, wgf, wpack);
    hipLaunchKernelGGL(moe_main, dim3(NBLK), dim3(TPB), 0, stream,
                       num_prop, flag, wgf, bpp, wpack, cnt1, out2);
    hipLaunchKernelGGL(finalize_kernel, dim3(1), dim3(1), 0, stream,
                       cnt1, outf + (size_t)NTOK * 2);
}